// Round 5
// baseline (313.987 us; speedup 1.0000x reference)
//
#include <hip/hip_runtime.h>
#include <math.h>

#define TPB 256

// ---------------- layer geometry ----------------
constexpr int DIMS_[5]  = {480, 240, 120, 60, 30};
constexpr int CHS_ [5]  = {64, 128, 256, 512, 512};
constexpr int CHB_ [5]  = {0, 64, 192, 448, 960};
constexpr int TOTCH     = 1472;
constexpr int PROCB_[5] = {0, 230400, 288000, 302400, 306000};
constexpr int PROCTOT   = 306900;

// ---------------- ws layout (4-byte words) ----------------
constexpr int O_CHMIN = 0;                  // f32 [1472]
constexpr int O_CHMAX = 1472;               // f32 [1472]
constexpr int O_HIST  = 2944;               // u32 [1472*6]
constexpr int O_GCNT  = 11776;              // u32 [1472*6]
constexpr int O_CLUT  = 20608;              // f32 [1472*16]: unused[5], gthr[5], lut[6]
constexpr int O_BSUM  = O_CLUT + 16 * 1472; // 44160: f32 [5]
constexpr int O_PMIN  = O_BSUM + 5;         // u32 [5]
constexpr int O_PMAX  = O_PMIN + 5;         // u32 [5]
constexpr int O_S3MIN = O_PMAX + 5;         // u32 [5]
constexpr int O_S3MAX = O_S3MIN + 5;        // u32 [5]
constexpr int O_S3SUM = O_S3MAX + 5;        // f32 [5]
constexpr int O_PROC  = 44192;              // f32 [306900] (L1..L4 zero-init; atomicAdd)
constexpr int O_RESZ  = O_PROC + PROCTOT;   // f32 [5*57600]
// init: stats region + proc words [230400, 306900) (L0 proc fully written by kC)
constexpr int N_STAT  = O_PROC;
constexpr int N_PZ    = PROCTOT - PROCB_[1];   // 76500
constexpr int N_INIT  = N_STAT + N_PZ;

struct P {
  const float* in[5];
  float* ws;
};

// ---------------- threshold helpers ----------------
// hb >= k+1  <=>  v >= mn + rng*(k+1)/6       (k = 0..4)
// gb >= k+1  <=>  v >= mn + rng*(k+2)/1536    (k = 0..4)
__device__ __forceinline__ void mk_hthr(float mn, float rng, float* th) {
  if (rng == 0.0f) { th[0]=th[1]=th[2]=th[3]=th[4]=INFINITY; return; }
  th[0] = mn + rng * (1.0f / 6.0f); th[1] = mn + rng * (2.0f / 6.0f);
  th[2] = mn + rng * (3.0f / 6.0f); th[3] = mn + rng * (4.0f / 6.0f);
  th[4] = mn + rng * (5.0f / 6.0f);
}
__device__ __forceinline__ void mk_gthr(float mn, float rng, float* tg) {
  if (rng == 0.0f) { tg[0]=tg[1]=tg[2]=tg[3]=tg[4]=INFINITY; return; }
  tg[0] = mn + rng * (2.0f / 1536.0f); tg[1] = mn + rng * (3.0f / 1536.0f);
  tg[2] = mn + rng * (4.0f / 1536.0f); tg[3] = mn + rng * (5.0f / 1536.0f);
  tg[4] = mn + rng * (6.0f / 1536.0f);
}

// zero border components of a float4 covering f4-index f4i (D % 4 == 0 path)
template <int D>
__device__ __forceinline__ void border_zero_f4(int f4i, float4& v) {
  constexpr int DQ = D / 4;
  if constexpr (D % 4 == 0) {
    int y = f4i / DQ, xq = f4i - y * DQ;
    if (y == 0 || y == D - 1) { v.x = v.y = v.z = v.w = 0.0f; }
    else {
      if (xq == 0)      v.x = 0.0f;
      if (xq == DQ - 1) v.w = 0.0f;
    }
  } else {   // D == 30: f4 may straddle rows
    int e0 = f4i * 4;
    float* c = (float*)&v;
    #pragma unroll
    for (int j = 0; j < 4; j++) {
      int e = e0 + j, y = e / D, x = e - y * D;
      bool inr = ((unsigned)(x - 1) < (unsigned)(D - 2)) && ((unsigned)(y - 1) < (unsigned)(D - 2));
      if (!inr) c[j] = 0.0f;
    }
  }
}

// ---------------- init ----------------
__global__ void k_init(float* ws) {
  int i = blockIdx.x * TPB + threadIdx.x;
  if (i >= N_INIT) return;
  if (i < N_STAT) {
    unsigned v = 0u;
    if (i < O_CHMAX) v = 0x7F800000u;                       // chmin = +inf
    else if (i >= O_PMIN  && i < O_PMAX)  v = 0x7F800000u;  // pmin
    else if (i >= O_S3MIN && i < O_S3MAX) v = 0x7F800000u;  // s3min
    ((unsigned*)ws)[i] = v;
  } else {
    ws[O_PROC + PROCB_[1] + (i - N_STAT)] = 0.0f;
  }
}

// ---- pass A: per-channel min/max of border-zeroed map (float4, 4-deep batched loads) ----
template <int L>
__device__ void bodyA(int local, const float* __restrict__ in, float* ws) {
  constexpr int D = DIMS_[L], HW = D * D, HW4 = HW / 4;
  constexpr int BPC = (HW4 + 4095) / 4096;
  int ch = local / BPC, chunk = local % BPC;
  int base = chunk * 4096;
  int nvec = HW4 - base; if (nvec > 4096) nvec = 4096;
  const float4* pv = (const float4*)(in + (size_t)ch * HW) + base;
  int t = threadIdx.x;
  float mn = INFINITY, mx = 0.0f;
  for (int o = 0; o < 4; o++) {
    float4 v[4];
    #pragma unroll
    for (int q = 0; q < 4; q++) {
      int vi = (o * 4 + q) * TPB + t;
      float4 vv = make_float4(0.0f, 0.0f, 0.0f, 0.0f);   // sentinel: exact (map has zeros)
      if (vi < nvec) {
        vv = pv[vi];
        border_zero_f4<D>(base + vi, vv);
      }
      v[q] = vv;
    }
    #pragma unroll
    for (int q = 0; q < 4; q++) {
      mn = fminf(mn, fminf(fminf(v[q].x, v[q].y), fminf(v[q].z, v[q].w)));
      mx = fmaxf(mx, fmaxf(fmaxf(v[q].x, v[q].y), fmaxf(v[q].z, v[q].w)));
    }
  }
  for (int o = 32; o; o >>= 1) { mn = fminf(mn, __shfl_down(mn, o)); mx = fmaxf(mx, __shfl_down(mx, o)); }
  __shared__ float smn[4], smx[4];
  int w = t >> 6;
  if ((t & 63) == 0) { smn[w] = mn; smx[w] = mx; }
  __syncthreads();
  if (t == 0) {
    mn = fminf(fminf(smn[0], smn[1]), fminf(smn[2], smn[3]));
    mx = fmaxf(fmaxf(smx[0], smx[1]), fmaxf(smx[2], smx[3]));
    int g = CHB_[L] + ch;
    atomicMin((unsigned*)ws + O_CHMIN + g, __float_as_uint(mn));  // values >= 0
    atomicMax((unsigned*)ws + O_CHMAX + g, __float_as_uint(mx));
  }
}
__global__ void kA(P p) {
  int b = blockIdx.x;
  if      (b <  960) bodyA<0>(b,        p.in[0], p.ws);
  else if (b < 1472) bodyA<1>(b -  960, p.in[1], p.ws);
  else if (b < 1728) bodyA<2>(b - 1472, p.in[2], p.ws);
  else if (b < 2240) bodyA<3>(b - 1728, p.in[3], p.ws);
  else               bodyA<4>(b - 2240, p.in[4], p.ws);
}

// ---- pass B: hist + gidx counts via ballots; 4-deep batched loads; -inf sentinel ----
template <int L>
__device__ void bodyB(int local, const float* __restrict__ in, float* ws) {
  constexpr int D = DIMS_[L], HW = D * D, HW4 = HW / 4;
  constexpr int BPC = (HW4 + 4095) / 4096;
  int ch = local / BPC, chunk = local % BPC;
  int g = CHB_[L] + ch;
  float mn = ws[O_CHMIN + g], mx = ws[O_CHMAX + g], rng = mx - mn;
  float th[5], tg[5];
  mk_hthr(mn, rng, th);
  mk_gthr(mn, rng, tg);
  int base = chunk * 4096;
  int nvec = HW4 - base; if (nvec > 4096) nvec = 4096;
  const float4* pv = (const float4*)(in + (size_t)ch * HW) + base;
  int t = threadIdx.x;
  unsigned cH0 = 0, cH1 = 0, cH2 = 0, cH3 = 0, cH4 = 0;
  unsigned cG0 = 0, cG1 = 0, cG2 = 0, cG3 = 0, cG4 = 0, nv4 = 0;
  for (int o = 0; o < 4; o++) {
    float4 v[4];
    #pragma unroll
    for (int q = 0; q < 4; q++) {
      int vi = (o * 4 + q) * TPB + t;
      float4 vv = make_float4(-INFINITY, -INFINITY, -INFINITY, -INFINITY);  // fails all >= tests
      if (vi < nvec) {
        vv = pv[vi];
        border_zero_f4<D>(base + vi, vv);
      }
      v[q] = vv;
    }
    #pragma unroll
    for (int q = 0; q < 4; q++) {
      int vi = (o * 4 + q) * TPB + t;
      nv4 += __popcll(__ballot(vi < nvec));
      float vv[4] = {v[q].x, v[q].y, v[q].z, v[q].w};
      #pragma unroll
      for (int j = 0; j < 4; j++) {
        float x = vv[j];
        cH0 += __popcll(__ballot(x >= th[0])); cH1 += __popcll(__ballot(x >= th[1]));
        cH2 += __popcll(__ballot(x >= th[2])); cH3 += __popcll(__ballot(x >= th[3]));
        cH4 += __popcll(__ballot(x >= th[4]));
        cG0 += __popcll(__ballot(x >= tg[0])); cG1 += __popcll(__ballot(x >= tg[1]));
        cG2 += __popcll(__ballot(x >= tg[2])); cG3 += __popcll(__ballot(x >= tg[3]));
        cG4 += __popcll(__ballot(x >= tg[4]));
      }
    }
  }
  if ((t & 63) == 0) {
    unsigned tot = nv4 * 4u;
    unsigned* H = (unsigned*)ws + O_HIST + g * 6;
    unsigned* G = (unsigned*)ws + O_GCNT + g * 6;
    atomicAdd(H + 0, tot - cH0); atomicAdd(H + 1, cH0 - cH1);
    atomicAdd(H + 2, cH1 - cH2); atomicAdd(H + 3, cH2 - cH3);
    atomicAdd(H + 4, cH3 - cH4); atomicAdd(H + 5, cH4);
    atomicAdd(G + 0, tot - cG0); atomicAdd(G + 1, cG0 - cG1);
    atomicAdd(G + 2, cG1 - cG2); atomicAdd(G + 3, cG2 - cG3);
    atomicAdd(G + 4, cG3 - cG4); atomicAdd(G + 5, cG4);
  }
}
__global__ void kB(P p) {
  int b = blockIdx.x;
  if      (b <  960) bodyB<0>(b,        p.in[0], p.ws);
  else if (b < 1472) bodyB<1>(b -  960, p.in[1], p.ws);
  else if (b < 1728) bodyB<2>(b - 1472, p.in[2], p.ws);
  else if (b < 2240) bodyB<3>(b - 1728, p.in[3], p.ws);
  else               bodyB<4>(b - 2240, p.in[4], p.ws);
}

// ---------------- kernel S: per-channel LUT construction ----------------
__global__ void kS(P p) {
  int ch = blockIdx.x * TPB + threadIdx.x;
  if (ch >= TOTCH) return;
  float* ws = p.ws;
  int l = (ch < 64) ? 0 : (ch < 192) ? 1 : (ch < 448) ? 2 : (ch < 960) ? 3 : 4;
  int D = DIMS_[l];
  int HW = D * D;
  int c0 = ch - CHB_[l];
  unsigned hc[6], gc[6];
  unsigned* H = (unsigned*)ws + O_HIST + ch * 6;
  unsigned* G = (unsigned*)ws + O_GCNT + ch * 6;
  #pragma unroll
  for (int k = 0; k < 6; k++) { hc[k] = H[k]; gc[k] = G[k]; }
  float HWf = (float)HW;
  float nh[6];
  #pragma unroll
  for (int k = 0; k < 6; k++) nh[k] = -logf((float)hc[k] / HWf + 1e-4f);
  float dmn = INFINITY, dmx = -INFINITY;
  #pragma unroll
  for (int k = 0; k < 6; k++) if (gc[k]) { dmn = fminf(dmn, nh[k]); dmx = fmaxf(dmx, nh[k]); }
  float dr = dmx - dmn;
  float dstn[6];
  #pragma unroll
  for (int k = 0; k < 6; k++) dstn[k] = (dr == 0.0f) ? 0.0f : ((nh[k] - dmn) / dr);
  float maxv = (dr == 0.0f) ? 0.0f : 1.0f;
  double s1 = 0.0;
  #pragma unroll
  for (int k = 0; k < 6; k++) s1 += (double)gc[k] * (double)dstn[k];
  float mean1 = (float)(s1 / (double)HW);
  float w1 = maxv - mean1; w1 *= w1;
  float lut1[6];
  #pragma unroll
  for (int k = 0; k < 6; k++) lut1[k] = dstn[k] * w1;
  float mnc = ws[O_CHMIN + ch], mxc = ws[O_CHMAX + ch];
  float tg[5];
  mk_gthr(mnc, mxc - mnc, tg);
  int gb = (0.0f >= tg[0]) + (0.0f >= tg[1]) + (0.0f >= tg[2]) + (0.0f >= tg[3]) + (0.0f >= tg[4]);
  unsigned bcnt = (unsigned)(4 * D - 4);
  float lmn, lmx;
  double s2 = 0.0;
  if (c0 == 0) {   // channel 0 keeps its border
    lmn = INFINITY; lmx = -INFINITY;
    #pragma unroll
    for (int k = 0; k < 6; k++) if (gc[k]) {
      lmn = fminf(lmn, lut1[k]); lmx = fmaxf(lmx, lut1[k]);
      s2 += (double)gc[k] * (double)lut1[k];
    }
  } else {
    lmn = 0.0f; lmx = 0.0f;   // border zeros present
    #pragma unroll
    for (int k = 0; k < 6; k++) {
      unsigned ic = gc[k] - ((k == gb) ? bcnt : 0u);
      if (ic) {
        lmn = fminf(lmn, lut1[k]); lmx = fmaxf(lmx, lut1[k]);
        s2 += (double)ic * (double)lut1[k];
      }
    }
  }
  float mean2 = (float)(s2 / (double)HW);
  float w2 = lmx - mean2; w2 *= w2;
  float r2 = lmx - lmn;
  float lout[6];
  #pragma unroll
  for (int k = 0; k < 6; k++) lout[k] = (r2 == 0.0f) ? 0.0f : (((lut1[k] - lmn) / r2) * w2);
  float* T = ws + O_CLUT + (size_t)ch * 16;
  #pragma unroll
  for (int k = 0; k < 5; k++) T[5 + k] = tg[k];
  #pragma unroll
  for (int k = 0; k < 6; k++) T[10 + k] = lout[k];
  float bc = (c0 == 0) ? lout[gb] : ((r2 == 0.0f) ? 0.0f : (((0.0f - lmn) / r2) * w2));
  atomicAdd(ws + O_BSUM + l, bc);
}

// ---- pass C: proc = sum_c LUT[gb_c(v)] ----
// Uniform work units: (64-float4 tile) x (64-channel chunk). L0 (NCH==1) fuses
// the per-layer proc min/max (kD covers only chunked layers).
template <int L>
__device__ void bodyC(int local, const float* __restrict__ in, float* ws,
                      float* slut, float* sred) {
  constexpr int D = DIMS_[L], HW = D * D, HW4 = HW / 4, C = CHS_[L];
  constexpr int NT  = (HW4 + 63) / 64;   // tiles per layer
  constexpr int NCH = C / 64;            // channel chunks
  int tile = local % NT, chunk = local / NT;
  int cbase = CHB_[L] + chunk * 64;
  int t = threadIdx.x, lane = t & 63, w = t >> 6;
  const float* gl = ws + O_CLUT + (size_t)cbase * 16;
  for (int i = t; i < 1024; i += TPB) slut[i] = gl[i];
  __syncthreads();
  int p4 = tile * 64 + lane;
  bool valid = p4 < HW4;
  float a0 = 0.0f, a1 = 0.0f, a2 = 0.0f, a3 = 0.0f;
  if (valid) {
    const float4* bp = (const float4*)in + (size_t)(chunk * 64 + w * 16) * HW4 + p4;
    const float* su = slut + (w * 16) * 16;
    #pragma unroll 4
    for (int c = 0; c < 16; c++) {
      float4 v = bp[(size_t)c * HW4];
      const float* cl = su + c * 16 + 5;
      float g0 = cl[0], g1 = cl[1], g2 = cl[2], g3 = cl[3], g4 = cl[4];
      float l0 = cl[5], l1 = cl[6], l2 = cl[7], l3 = cl[8], l4 = cl[9], l5 = cl[10];
      float s;
      s = (v.x >= g0) ? l1 : l0; s = (v.x >= g1) ? l2 : s; s = (v.x >= g2) ? l3 : s;
      s = (v.x >= g3) ? l4 : s;  s = (v.x >= g4) ? l5 : s; a0 += s;
      s = (v.y >= g0) ? l1 : l0; s = (v.y >= g1) ? l2 : s; s = (v.y >= g2) ? l3 : s;
      s = (v.y >= g3) ? l4 : s;  s = (v.y >= g4) ? l5 : s; a1 += s;
      s = (v.z >= g0) ? l1 : l0; s = (v.z >= g1) ? l2 : s; s = (v.z >= g2) ? l3 : s;
      s = (v.z >= g3) ? l4 : s;  s = (v.z >= g4) ? l5 : s; a2 += s;
      s = (v.w >= g0) ? l1 : l0; s = (v.w >= g1) ? l2 : s; s = (v.w >= g2) ? l3 : s;
      s = (v.w >= g3) ? l4 : s;  s = (v.w >= g4) ? l5 : s; a3 += s;
    }
  }
  sred[0 * 256 + w * 64 + lane] = a0;
  sred[1 * 256 + w * 64 + lane] = a1;
  sred[2 * 256 + w * 64 + lane] = a2;
  sred[3 * 256 + w * 64 + lane] = a3;
  __syncthreads();
  if (w == 0) {
    float o[4];
    #pragma unroll
    for (int j = 0; j < 4; j++)
      o[j] = sred[j * 256 + lane] + sred[j * 256 + 64 + lane] +
             sred[j * 256 + 128 + lane] + sred[j * 256 + 192 + lane];
    float bs = ws[O_BSUM + L];
    float* procL = ws + O_PROC + PROCB_[L];
    int px0 = p4 * 4;
    if constexpr (NCH == 1) {
      float mn = INFINITY, mx = 0.0f;
      if (valid) {
        #pragma unroll
        for (int j = 0; j < 4; j++) {
          int px = px0 + j, y = px / D, x = px - y * D;
          bool inr = ((unsigned)(x - 1) < (unsigned)(D - 2)) && ((unsigned)(y - 1) < (unsigned)(D - 2));
          if (!inr) o[j] = bs;
        }
        ((float4*)procL)[p4] = make_float4(o[0], o[1], o[2], o[3]);
        mn = fminf(fminf(o[0], o[1]), fminf(o[2], o[3]));
        mx = fmaxf(fmaxf(o[0], o[1]), fmaxf(o[2], o[3]));
      }
      for (int s = 32; s; s >>= 1) { mn = fminf(mn, __shfl_down(mn, s)); mx = fmaxf(mx, __shfl_down(mx, s)); }
      if (lane == 0) {
        atomicMin((unsigned*)ws + O_PMIN + L, __float_as_uint(mn));
        atomicMax((unsigned*)ws + O_PMAX + L, __float_as_uint(mx));
      }
    } else if (valid) {
      #pragma unroll
      for (int j = 0; j < 4; j++) {
        int px = px0 + j, y = px / D, x = px - y * D;
        bool inr = ((unsigned)(x - 1) < (unsigned)(D - 2)) && ((unsigned)(y - 1) < (unsigned)(D - 2));
        if (inr) atomicAdd(procL + px, o[j]);
        else if (chunk == 0) procL[px] = bs;   // sole writer of border pixels
      }
    }
  }
}
__global__ __launch_bounds__(TPB) void kC(P p) {
  __shared__ float slut[1024];
  __shared__ float sred[1024];
  int b = blockIdx.x;
  if      (b <  900) bodyC<0>(b,        p.in[0], p.ws, slut, sred);
  else if (b < 1350) bodyC<1>(b -  900, p.in[1], p.ws, slut, sred);
  else if (b < 1578) bodyC<2>(b - 1350, p.in[2], p.ws, slut, sred);
  else if (b < 1698) bodyC<3>(b - 1578, p.in[3], p.ws, slut, sred);
  else               bodyC<4>(b - 1698, p.in[4], p.ws, slut, sred);
}

// ---------------- pass D: per-layer proc min/max (layers 1..4 only) ----------------
template <int L>
__device__ void bodyD(int chunk, float* ws) {
  constexpr int HW = DIMS_[L] * DIMS_[L];
  const float* pr = ws + O_PROC + PROCB_[L];
  int t = threadIdx.x;
  float mn = INFINITY, mx = 0.0f;   // proc >= 0
  #pragma unroll
  for (int i = 0; i < 16; i++) {
    int idx = chunk * 4096 + i * TPB + t;
    if (idx < HW) { float v = pr[idx]; mn = fminf(mn, v); mx = fmaxf(mx, v); }
  }
  for (int o = 32; o; o >>= 1) { mn = fminf(mn, __shfl_down(mn, o)); mx = fmaxf(mx, __shfl_down(mx, o)); }
  __shared__ float smn[4], smx[4];
  int w = t >> 6;
  if ((t & 63) == 0) { smn[w] = mn; smx[w] = mx; }
  __syncthreads();
  if (t == 0) {
    mn = fminf(fminf(smn[0], smn[1]), fminf(smn[2], smn[3]));
    mx = fmaxf(fmaxf(smx[0], smx[1]), fmaxf(smx[2], smx[3]));
    atomicMin((unsigned*)ws + O_PMIN + L, __float_as_uint(mn));
    atomicMax((unsigned*)ws + O_PMAX + L, __float_as_uint(mx));
  }
}
__global__ void kD(P p) {
  int b = blockIdx.x;
  if      (b < 15) bodyD<1>(b,      p.ws);
  else if (b < 19) bodyD<2>(b - 15, p.ws);
  else if (b < 20) bodyD<3>(b - 19, p.ws);
  else             bodyD<4>(b - 20, p.ws);
}

// ---- pass F: normalize(proc,0,1) + threshold + jax bilinear resize, fused layer stats ----
template <int L>
__device__ float bodyF(int px, float* ws) {
  constexpr int D = DIMS_[L];
  constexpr float INV = (float)D / 240.0f;
  constexpr float KS = (INV > 1.0f) ? INV : 1.0f;
  int oy = px / 240, ox = px - oy * 240;
  float mnv = __uint_as_float(((unsigned*)ws)[O_PMIN + L]);
  float mxv = __uint_as_float(((unsigned*)ws)[O_PMAX + L]);
  float pr = mxv - mnv;
  const float* procL = ws + O_PROC + PROCB_[L];
  float sfy = ((float)oy + 0.5f) * INV - 0.5f;
  float sfx = ((float)ox + 0.5f) * INV - 0.5f;
  int y0 = (int)ceilf(sfy - KS);  if (y0 < 0) y0 = 0;
  int y1 = (int)floorf(sfy + KS); if (y1 > D - 1) y1 = D - 1;
  int x0 = (int)ceilf(sfx - KS);  if (x0 < 0) x0 = 0;
  int x1 = (int)floorf(sfx + KS); if (x1 > D - 1) x1 = D - 1;
  float wsx = 0.0f;
  for (int jx = x0; jx <= x1; jx++) wsx += fmaxf(1.0f - fabsf(sfx - (float)jx) / KS, 0.0f);
  float acc = 0.0f, wsy = 0.0f;
  for (int jy = y0; jy <= y1; jy++) {
    float wy = fmaxf(1.0f - fabsf(sfy - (float)jy) / KS, 0.0f);
    wsy += wy;
    if (wy > 0.0f) {
      const float* row = procL + jy * D;
      float rs = 0.0f;
      for (int jx = x0; jx <= x1; jx++) {
        float wx = fmaxf(1.0f - fabsf(sfx - (float)jx) / KS, 0.0f);
        if (wx > 0.0f) {
          float v = row[jx];
          float tv = (pr == 0.0f) ? 0.0f : ((v - mnv) / pr);
          tv = (tv < 0.2f) ? 0.0f : tv;
          rs += wx * tv;
        }
      }
      acc += wy * rs;
    }
  }
  return acc / (wsy * wsx);
}
__global__ void kF(P p) {
  float* ws = p.ws;
  int b = blockIdx.x, l = b / 225;
  int px = (b - l * 225) * TPB + threadIdx.x;
  float res;
  switch (l) {
    case 0: res = bodyF<0>(px, ws); break;
    case 1: res = bodyF<1>(px, ws); break;
    case 2: res = bodyF<2>(px, ws); break;
    case 3: res = bodyF<3>(px, ws); break;
    default: res = bodyF<4>(px, ws); break;
  }
  ws[O_RESZ + l * 57600 + px] = res;
  float mn = res, mx = res, s = res;
  for (int o = 32; o; o >>= 1) {
    mn = fminf(mn, __shfl_down(mn, o));
    mx = fmaxf(mx, __shfl_down(mx, o));
    s += __shfl_down(s, o);
  }
  __shared__ float smn[4], smx[4], ssm[4];
  int t = threadIdx.x, w = t >> 6;
  if ((t & 63) == 0) { smn[w] = mn; smx[w] = mx; ssm[w] = s; }
  __syncthreads();
  if (t == 0) {
    mn = fminf(fminf(smn[0], smn[1]), fminf(smn[2], smn[3]));
    mx = fmaxf(fmaxf(smx[0], smx[1]), fmaxf(smx[2], smx[3]));
    s = ssm[0] + ssm[1] + ssm[2] + ssm[3];
    atomicMin((unsigned*)ws + O_S3MIN + l, __float_as_uint(mn));
    atomicMax((unsigned*)ws + O_S3MAX + l, __float_as_uint(mx));
    atomicAdd(ws + O_S3SUM + l, s);
  }
}

// ---------------- G2: final ponder + normalize(.,0,256), groups + sum ----------------
__global__ void kG2(P p, float* __restrict__ out) {
  float* ws = p.ws;
  int px = blockIdx.x * TPB + threadIdx.x;   // 225*256 == 57600
  float sum = 0.0f;
  #pragma unroll
  for (int l = 0; l < 5; l++) {
    float v = ws[O_RESZ + l * 57600 + px];
    float mn3 = __uint_as_float(((unsigned*)ws)[O_S3MIN + l]);
    float mx3 = __uint_as_float(((unsigned*)ws)[O_S3MAX + l]);
    float mean3 = ws[O_S3SUM + l] / 57600.0f;
    float r3 = mx3 - mn3;
    float ov;
    if (r3 == 0.0f) ov = 0.0f;
    else {
      float w3 = mx3 - mean3; w3 *= w3;
      if (w3 == 0.0f) ov = 0.0f;
      else ov = ((v - mn3) / r3) * w3 / w3 * 256.0f;
    }
    out[57600 + px * 5 + l] = ov;
    sum += ov;
  }
  out[px] = sum;
}

extern "C" void kernel_launch(void* const* d_in, const int* in_sizes, int n_in,
                              void* d_out, int out_size, void* d_ws, size_t ws_size,
                              hipStream_t stream) {
  (void)in_sizes; (void)n_in; (void)out_size; (void)ws_size;
  P p;
  for (int i = 0; i < 5; i++) p.in[i] = (const float*)d_in[i];
  p.ws = (float*)d_ws;
  float* out = (float*)d_out;

  k_init<<<(N_INIT + TPB - 1) / TPB, TPB, 0, stream>>>(p.ws);
  kA  <<<2752, TPB, 0, stream>>>(p);
  kB  <<<2752, TPB, 0, stream>>>(p);
  kS  <<<6,    TPB, 0, stream>>>(p);
  kC  <<<1730, TPB, 0, stream>>>(p);
  kD  <<<21,   TPB, 0, stream>>>(p);
  kF  <<<1125, TPB, 0, stream>>>(p);
  kG2 <<<225,  TPB, 0, stream>>>(p, out);
}

// Round 6
// 303.090 us; speedup vs baseline: 1.0360x; 1.0360x over previous
//
#include <hip/hip_runtime.h>
#include <math.h>

#define TPB 256

// ---------------- layer geometry ----------------
constexpr int DIMS_[5]  = {480, 240, 120, 60, 30};
constexpr int CHS_ [5]  = {64, 128, 256, 512, 512};
constexpr int CHB_ [5]  = {0, 64, 192, 448, 960};
constexpr int TOTCH     = 1472;
constexpr int PROCB_[5] = {0, 230400, 288000, 302400, 306000};
constexpr int PROCTOT   = 306900;

// ---------------- ws layout (4-byte words) ----------------
constexpr int O_CHMIN = 0;                  // f32 [1472]
constexpr int O_CHMAX = 1472;               // f32 [1472]
constexpr int O_HIST  = 2944;               // u32 [1472*6]
constexpr int O_GCNT  = 11776;              // u32 [1472*6]
constexpr int O_CLUT  = 20608;              // f32 [1472*16]: unused[5], gthr[5], lut[6]
constexpr int O_BSUM  = O_CLUT + 16 * 1472; // 44160: f32 [5]
constexpr int O_PMIN  = O_BSUM + 5;         // u32 [5]
constexpr int O_PMAX  = O_PMIN + 5;         // u32 [5]
constexpr int O_S3MIN = O_PMAX + 5;         // u32 [5]
constexpr int O_S3MAX = O_S3MIN + 5;        // u32 [5]
constexpr int O_S3SUM = O_S3MAX + 5;        // f32 [5]
constexpr int O_PROC  = 44192;              // f32 [306900] (L1..L4 zero-init; atomicAdd)
constexpr int O_RESZ  = O_PROC + PROCTOT;   // f32 [5*57600]
constexpr int N_STAT  = O_PROC;
constexpr int N_PZ    = PROCTOT - PROCB_[1];   // 76500 (L0 proc fully written by kC)
constexpr int N_INIT  = N_STAT + N_PZ;

struct P {
  const float* in[5];
  float* ws;
};

// ---------------- threshold helpers ----------------
// hb >= k+1  <=>  v >= mn + rng*(k+1)/6       (k = 0..4)
// gb >= k+1  <=>  v >= mn + rng*(k+2)/1536    (k = 0..4)
__device__ __forceinline__ void mk_hthr(float mn, float rng, float* th) {
  if (rng == 0.0f) { th[0]=th[1]=th[2]=th[3]=th[4]=INFINITY; return; }
  th[0] = mn + rng * (1.0f / 6.0f); th[1] = mn + rng * (2.0f / 6.0f);
  th[2] = mn + rng * (3.0f / 6.0f); th[3] = mn + rng * (4.0f / 6.0f);
  th[4] = mn + rng * (5.0f / 6.0f);
}
__device__ __forceinline__ void mk_gthr(float mn, float rng, float* tg) {
  if (rng == 0.0f) { tg[0]=tg[1]=tg[2]=tg[3]=tg[4]=INFINITY; return; }
  tg[0] = mn + rng * (2.0f / 1536.0f); tg[1] = mn + rng * (3.0f / 1536.0f);
  tg[2] = mn + rng * (4.0f / 1536.0f); tg[3] = mn + rng * (5.0f / 1536.0f);
  tg[4] = mn + rng * (6.0f / 1536.0f);
}

// zero border components of a float4 covering f4-index f4i
template <int D>
__device__ __forceinline__ void border_zero_f4(int f4i, float4& v) {
  constexpr int DQ = D / 4;
  if constexpr (D % 4 == 0) {          // whole f4 on one row
    int y = f4i / DQ, xq = f4i - y * DQ;
    if (y == 0 || y == D - 1) { v.x = v.y = v.z = v.w = 0.0f; }
    else {
      if (xq == 0)      v.x = 0.0f;
      if (xq == DQ - 1) v.w = 0.0f;
    }
  } else {                             // D == 30: f4 may straddle rows
    int e0 = f4i * 4;
    float* c = (float*)&v;
    #pragma unroll
    for (int j = 0; j < 4; j++) {
      int e = e0 + j, y = e / D, x = e - y * D;
      bool inr = ((unsigned)(x - 1) < (unsigned)(D - 2)) && ((unsigned)(y - 1) < (unsigned)(D - 2));
      if (!inr) c[j] = 0.0f;
    }
  }
}

// ---------------- init ----------------
__global__ void k_init(float* ws) {
  int i = blockIdx.x * TPB + threadIdx.x;
  if (i >= N_INIT) return;
  if (i < N_STAT) {
    unsigned v = 0u;
    if (i < O_CHMAX) v = 0x7F800000u;                       // chmin = +inf
    else if (i >= O_PMIN  && i < O_PMAX)  v = 0x7F800000u;  // pmin
    else if (i >= O_S3MIN && i < O_S3MAX) v = 0x7F800000u;  // s3min
    ((unsigned*)ws)[i] = v;
  } else {
    ws[O_PROC + PROCB_[1] + (i - N_STAT)] = 0.0f;
  }
}

// ---- pass A: per-channel min/max of border-zeroed map (float4 stream) ----
template <int L>
__device__ void bodyA(int local, const float* __restrict__ in, float* ws) {
  constexpr int D = DIMS_[L], HW = D * D, HW4 = HW / 4;
  constexpr int BPC = (HW4 + 4095) / 4096;
  int ch = local / BPC, chunk = local % BPC;
  int base = chunk * 4096;
  int nvec = HW4 - base; if (nvec > 4096) nvec = 4096;
  const float4* pv = (const float4*)(in + (size_t)ch * HW) + base;
  int t = threadIdx.x;
  float mn = INFINITY, mx = 0.0f;   // values >= 0; border zeros exist
  #pragma unroll 4
  for (int i = 0; i < 16; i++) {
    int vi = i * TPB + t;
    if (vi < nvec) {
      float4 v = pv[vi];
      border_zero_f4<D>(base + vi, v);
      mn = fminf(mn, fminf(fminf(v.x, v.y), fminf(v.z, v.w)));
      mx = fmaxf(mx, fmaxf(fmaxf(v.x, v.y), fmaxf(v.z, v.w)));
    }
  }
  for (int o = 32; o; o >>= 1) { mn = fminf(mn, __shfl_down(mn, o)); mx = fmaxf(mx, __shfl_down(mx, o)); }
  __shared__ float smn[4], smx[4];
  int w = t >> 6;
  if ((t & 63) == 0) { smn[w] = mn; smx[w] = mx; }
  __syncthreads();
  if (t == 0) {
    mn = fminf(fminf(smn[0], smn[1]), fminf(smn[2], smn[3]));
    mx = fmaxf(fmaxf(smx[0], smx[1]), fmaxf(smx[2], smx[3]));
    int g = CHB_[L] + ch;
    atomicMin((unsigned*)ws + O_CHMIN + g, __float_as_uint(mn));
    atomicMax((unsigned*)ws + O_CHMAX + g, __float_as_uint(mx));
  }
}
__global__ void kA(P p) {
  int b = blockIdx.x;
  if      (b <  960) bodyA<0>(b,        p.in[0], p.ws);
  else if (b < 1472) bodyA<1>(b -  960, p.in[1], p.ws);
  else if (b < 1728) bodyA<2>(b - 1472, p.in[2], p.ws);
  else if (b < 2240) bodyA<3>(b - 1728, p.in[3], p.ws);
  else               bodyA<4>(b - 2240, p.in[4], p.ws);
}

// ---- pass B: hist + gidx counts with per-lane VGPR counters (pure VALU hot loop) ----
template <int L>
__device__ void bodyB(int local, const float* __restrict__ in, float* ws) {
  constexpr int D = DIMS_[L], HW = D * D, HW4 = HW / 4;
  constexpr int BPC = (HW4 + 4095) / 4096;
  int ch = local / BPC, chunk = local % BPC;
  int g = CHB_[L] + ch;
  float mn = ws[O_CHMIN + g], mx = ws[O_CHMAX + g], rng = mx - mn;
  float th[5], tg[5];
  mk_hthr(mn, rng, th);
  mk_gthr(mn, rng, tg);
  int base = chunk * 4096;
  int nvec = HW4 - base; if (nvec > 4096) nvec = 4096;
  const float4* pv = (const float4*)(in + (size_t)ch * HW) + base;
  int t = threadIdx.x;
  unsigned cH0 = 0, cH1 = 0, cH2 = 0, cH3 = 0, cH4 = 0;
  unsigned cG0 = 0, cG1 = 0, cG2 = 0, cG3 = 0, cG4 = 0, cnt = 0;
  #pragma unroll 4
  for (int i = 0; i < 16; i++) {
    int vi = i * TPB + t;
    if (vi < nvec) {
      float4 v = pv[vi];
      border_zero_f4<D>(base + vi, v);
      cnt += 4;
      float vv[4] = {v.x, v.y, v.z, v.w};
      #pragma unroll
      for (int j = 0; j < 4; j++) {
        float x = vv[j];
        cH0 += (x >= th[0]); cH1 += (x >= th[1]); cH2 += (x >= th[2]);
        cH3 += (x >= th[3]); cH4 += (x >= th[4]);
        cG0 += (x >= tg[0]); cG1 += (x >= tg[1]); cG2 += (x >= tg[2]);
        cG3 += (x >= tg[3]); cG4 += (x >= tg[4]);
      }
    }
  }
  for (int o = 32; o; o >>= 1) {
    cH0 += __shfl_down(cH0, o); cH1 += __shfl_down(cH1, o); cH2 += __shfl_down(cH2, o);
    cH3 += __shfl_down(cH3, o); cH4 += __shfl_down(cH4, o);
    cG0 += __shfl_down(cG0, o); cG1 += __shfl_down(cG1, o); cG2 += __shfl_down(cG2, o);
    cG3 += __shfl_down(cG3, o); cG4 += __shfl_down(cG4, o);
    cnt += __shfl_down(cnt, o);
  }
  if ((t & 63) == 0) {
    unsigned* H = (unsigned*)ws + O_HIST + g * 6;
    unsigned* G = (unsigned*)ws + O_GCNT + g * 6;
    atomicAdd(H + 0, cnt - cH0); atomicAdd(H + 1, cH0 - cH1);
    atomicAdd(H + 2, cH1 - cH2); atomicAdd(H + 3, cH2 - cH3);
    atomicAdd(H + 4, cH3 - cH4); atomicAdd(H + 5, cH4);
    atomicAdd(G + 0, cnt - cG0); atomicAdd(G + 1, cG0 - cG1);
    atomicAdd(G + 2, cG1 - cG2); atomicAdd(G + 3, cG2 - cG3);
    atomicAdd(G + 4, cG3 - cG4); atomicAdd(G + 5, cG4);
  }
}
__global__ void kB(P p) {
  int b = blockIdx.x;
  if      (b <  960) bodyB<0>(b,        p.in[0], p.ws);
  else if (b < 1472) bodyB<1>(b -  960, p.in[1], p.ws);
  else if (b < 1728) bodyB<2>(b - 1472, p.in[2], p.ws);
  else if (b < 2240) bodyB<3>(b - 1728, p.in[3], p.ws);
  else               bodyB<4>(b - 2240, p.in[4], p.ws);
}

// ---------------- kernel S: per-channel LUT construction ----------------
__global__ void kS(P p) {
  int ch = blockIdx.x * TPB + threadIdx.x;
  if (ch >= TOTCH) return;
  float* ws = p.ws;
  int l = (ch < 64) ? 0 : (ch < 192) ? 1 : (ch < 448) ? 2 : (ch < 960) ? 3 : 4;
  int D = DIMS_[l];
  int HW = D * D;
  int c0 = ch - CHB_[l];
  unsigned hc[6], gc[6];
  unsigned* H = (unsigned*)ws + O_HIST + ch * 6;
  unsigned* G = (unsigned*)ws + O_GCNT + ch * 6;
  #pragma unroll
  for (int k = 0; k < 6; k++) { hc[k] = H[k]; gc[k] = G[k]; }
  float HWf = (float)HW;
  float nh[6];
  #pragma unroll
  for (int k = 0; k < 6; k++) nh[k] = -logf((float)hc[k] / HWf + 1e-4f);
  float dmn = INFINITY, dmx = -INFINITY;
  #pragma unroll
  for (int k = 0; k < 6; k++) if (gc[k]) { dmn = fminf(dmn, nh[k]); dmx = fmaxf(dmx, nh[k]); }
  float dr = dmx - dmn;
  float dstn[6];
  #pragma unroll
  for (int k = 0; k < 6; k++) dstn[k] = (dr == 0.0f) ? 0.0f : ((nh[k] - dmn) / dr);
  float maxv = (dr == 0.0f) ? 0.0f : 1.0f;
  double s1 = 0.0;
  #pragma unroll
  for (int k = 0; k < 6; k++) s1 += (double)gc[k] * (double)dstn[k];
  float mean1 = (float)(s1 / (double)HW);
  float w1 = maxv - mean1; w1 *= w1;
  float lut1[6];
  #pragma unroll
  for (int k = 0; k < 6; k++) lut1[k] = dstn[k] * w1;
  float mnc = ws[O_CHMIN + ch], mxc = ws[O_CHMAX + ch];
  float tg[5];
  mk_gthr(mnc, mxc - mnc, tg);
  int gb = (0.0f >= tg[0]) + (0.0f >= tg[1]) + (0.0f >= tg[2]) + (0.0f >= tg[3]) + (0.0f >= tg[4]);
  unsigned bcnt = (unsigned)(4 * D - 4);
  float lmn, lmx;
  double s2 = 0.0;
  if (c0 == 0) {   // channel 0 keeps its border
    lmn = INFINITY; lmx = -INFINITY;
    #pragma unroll
    for (int k = 0; k < 6; k++) if (gc[k]) {
      lmn = fminf(lmn, lut1[k]); lmx = fmaxf(lmx, lut1[k]);
      s2 += (double)gc[k] * (double)lut1[k];
    }
  } else {
    lmn = 0.0f; lmx = 0.0f;   // border zeros present
    #pragma unroll
    for (int k = 0; k < 6; k++) {
      unsigned ic = gc[k] - ((k == gb) ? bcnt : 0u);
      if (ic) {
        lmn = fminf(lmn, lut1[k]); lmx = fmaxf(lmx, lut1[k]);
        s2 += (double)ic * (double)lut1[k];
      }
    }
  }
  float mean2 = (float)(s2 / (double)HW);
  float w2 = lmx - mean2; w2 *= w2;
  float r2 = lmx - lmn;
  float lout[6];
  #pragma unroll
  for (int k = 0; k < 6; k++) lout[k] = (r2 == 0.0f) ? 0.0f : (((lut1[k] - lmn) / r2) * w2);
  float* T = ws + O_CLUT + (size_t)ch * 16;
  #pragma unroll
  for (int k = 0; k < 5; k++) T[5 + k] = tg[k];
  #pragma unroll
  for (int k = 0; k < 6; k++) T[10 + k] = lout[k];
  float bc = (c0 == 0) ? lout[gb] : ((r2 == 0.0f) ? 0.0f : (((0.0f - lmn) / r2) * w2));
  atomicAdd(ws + O_BSUM + l, bc);
}

// ---- pass C: proc = sum_c LUT[gb_c(v)] ----
template <int L>
__device__ void bodyC(int local, const float* __restrict__ in, float* ws,
                      float* slut, float* sred) {
  constexpr int D = DIMS_[L], HW = D * D, HW4 = HW / 4, C = CHS_[L];
  constexpr int NT  = (HW4 + 63) / 64;   // tiles per layer
  constexpr int NCH = C / 64;            // channel chunks
  int tile = local % NT, chunk = local / NT;
  int cbase = CHB_[L] + chunk * 64;
  int t = threadIdx.x, lane = t & 63, w = t >> 6;
  const float* gl = ws + O_CLUT + (size_t)cbase * 16;
  for (int i = t; i < 1024; i += TPB) slut[i] = gl[i];
  __syncthreads();
  int p4 = tile * 64 + lane;
  bool valid = p4 < HW4;
  float a0 = 0.0f, a1 = 0.0f, a2 = 0.0f, a3 = 0.0f;
  if (valid) {
    const float4* bp = (const float4*)in + (size_t)(chunk * 64 + w * 16) * HW4 + p4;
    const float* su = slut + (w * 16) * 16;
    #pragma unroll 4
    for (int c = 0; c < 16; c++) {
      float4 v = bp[(size_t)c * HW4];
      const float* cl = su + c * 16 + 5;
      float g0 = cl[0], g1 = cl[1], g2 = cl[2], g3 = cl[3], g4 = cl[4];
      float l0 = cl[5], l1 = cl[6], l2 = cl[7], l3 = cl[8], l4 = cl[9], l5 = cl[10];
      float s;
      s = (v.x >= g0) ? l1 : l0; s = (v.x >= g1) ? l2 : s; s = (v.x >= g2) ? l3 : s;
      s = (v.x >= g3) ? l4 : s;  s = (v.x >= g4) ? l5 : s; a0 += s;
      s = (v.y >= g0) ? l1 : l0; s = (v.y >= g1) ? l2 : s; s = (v.y >= g2) ? l3 : s;
      s = (v.y >= g3) ? l4 : s;  s = (v.y >= g4) ? l5 : s; a1 += s;
      s = (v.z >= g0) ? l1 : l0; s = (v.z >= g1) ? l2 : s; s = (v.z >= g2) ? l3 : s;
      s = (v.z >= g3) ? l4 : s;  s = (v.z >= g4) ? l5 : s; a2 += s;
      s = (v.w >= g0) ? l1 : l0; s = (v.w >= g1) ? l2 : s; s = (v.w >= g2) ? l3 : s;
      s = (v.w >= g3) ? l4 : s;  s = (v.w >= g4) ? l5 : s; a3 += s;
    }
  }
  sred[0 * 256 + w * 64 + lane] = a0;
  sred[1 * 256 + w * 64 + lane] = a1;
  sred[2 * 256 + w * 64 + lane] = a2;
  sred[3 * 256 + w * 64 + lane] = a3;
  __syncthreads();
  if (w == 0) {
    float o[4];
    #pragma unroll
    for (int j = 0; j < 4; j++)
      o[j] = sred[j * 256 + lane] + sred[j * 256 + 64 + lane] +
             sred[j * 256 + 128 + lane] + sred[j * 256 + 192 + lane];
    float bs = ws[O_BSUM + L];
    float* procL = ws + O_PROC + PROCB_[L];
    int px0 = p4 * 4;
    if constexpr (NCH == 1) {
      float mn = INFINITY, mx = 0.0f;
      if (valid) {
        #pragma unroll
        for (int j = 0; j < 4; j++) {
          int px = px0 + j, y = px / D, x = px - y * D;
          bool inr = ((unsigned)(x - 1) < (unsigned)(D - 2)) && ((unsigned)(y - 1) < (unsigned)(D - 2));
          if (!inr) o[j] = bs;
        }
        ((float4*)procL)[p4] = make_float4(o[0], o[1], o[2], o[3]);
        mn = fminf(fminf(o[0], o[1]), fminf(o[2], o[3]));
        mx = fmaxf(fmaxf(o[0], o[1]), fmaxf(o[2], o[3]));
      }
      for (int s = 32; s; s >>= 1) { mn = fminf(mn, __shfl_down(mn, s)); mx = fmaxf(mx, __shfl_down(mx, s)); }
      if (lane == 0) {
        atomicMin((unsigned*)ws + O_PMIN + L, __float_as_uint(mn));
        atomicMax((unsigned*)ws + O_PMAX + L, __float_as_uint(mx));
      }
    } else if (valid) {
      #pragma unroll
      for (int j = 0; j < 4; j++) {
        int px = px0 + j, y = px / D, x = px - y * D;
        bool inr = ((unsigned)(x - 1) < (unsigned)(D - 2)) && ((unsigned)(y - 1) < (unsigned)(D - 2));
        if (inr) atomicAdd(procL + px, o[j]);
        else if (chunk == 0) procL[px] = bs;   // sole writer of border pixels
      }
    }
  }
}
__global__ __launch_bounds__(TPB) void kC(P p) {
  __shared__ float slut[1024];
  __shared__ float sred[1024];
  int b = blockIdx.x;
  if      (b <  900) bodyC<0>(b,        p.in[0], p.ws, slut, sred);
  else if (b < 1350) bodyC<1>(b -  900, p.in[1], p.ws, slut, sred);
  else if (b < 1578) bodyC<2>(b - 1350, p.in[2], p.ws, slut, sred);
  else if (b < 1698) bodyC<3>(b - 1578, p.in[3], p.ws, slut, sred);
  else               bodyC<4>(b - 1698, p.in[4], p.ws, slut, sred);
}

// ---------------- pass D: per-layer proc min/max (layers 1..4 only) ----------------
template <int L>
__device__ void bodyD(int chunk, float* ws) {
  constexpr int HW = DIMS_[L] * DIMS_[L];
  const float* pr = ws + O_PROC + PROCB_[L];
  int t = threadIdx.x;
  float mn = INFINITY, mx = 0.0f;   // proc >= 0
  #pragma unroll
  for (int i = 0; i < 16; i++) {
    int idx = chunk * 4096 + i * TPB + t;
    if (idx < HW) { float v = pr[idx]; mn = fminf(mn, v); mx = fmaxf(mx, v); }
  }
  for (int o = 32; o; o >>= 1) { mn = fminf(mn, __shfl_down(mn, o)); mx = fmaxf(mx, __shfl_down(mx, o)); }
  __shared__ float smn[4], smx[4];
  int w = t >> 6;
  if ((t & 63) == 0) { smn[w] = mn; smx[w] = mx; }
  __syncthreads();
  if (t == 0) {
    mn = fminf(fminf(smn[0], smn[1]), fminf(smn[2], smn[3]));
    mx = fmaxf(fmaxf(smx[0], smx[1]), fmaxf(smx[2], smx[3]));
    atomicMin((unsigned*)ws + O_PMIN + L, __float_as_uint(mn));
    atomicMax((unsigned*)ws + O_PMAX + L, __float_as_uint(mx));
  }
}
__global__ void kD(P p) {
  int b = blockIdx.x;
  if      (b < 15) bodyD<1>(b,      p.ws);
  else if (b < 19) bodyD<2>(b - 15, p.ws);
  else if (b < 20) bodyD<3>(b - 19, p.ws);
  else             bodyD<4>(b - 20, p.ws);
}

// ---- pass F: normalize(proc,0,1) + threshold + jax bilinear resize, fused layer stats ----
template <int L>
__device__ float bodyF(int px, float* ws) {
  constexpr int D = DIMS_[L];
  constexpr float INV = (float)D / 240.0f;
  constexpr float KS = (INV > 1.0f) ? INV : 1.0f;
  int oy = px / 240, ox = px - oy * 240;
  float mnv = __uint_as_float(((unsigned*)ws)[O_PMIN + L]);
  float mxv = __uint_as_float(((unsigned*)ws)[O_PMAX + L]);
  float pr = mxv - mnv;
  const float* procL = ws + O_PROC + PROCB_[L];
  float sfy = ((float)oy + 0.5f) * INV - 0.5f;
  float sfx = ((float)ox + 0.5f) * INV - 0.5f;
  int y0 = (int)ceilf(sfy - KS);  if (y0 < 0) y0 = 0;
  int y1 = (int)floorf(sfy + KS); if (y1 > D - 1) y1 = D - 1;
  int x0 = (int)ceilf(sfx - KS);  if (x0 < 0) x0 = 0;
  int x1 = (int)floorf(sfx + KS); if (x1 > D - 1) x1 = D - 1;
  float wsx = 0.0f;
  for (int jx = x0; jx <= x1; jx++) wsx += fmaxf(1.0f - fabsf(sfx - (float)jx) / KS, 0.0f);
  float acc = 0.0f, wsy = 0.0f;
  for (int jy = y0; jy <= y1; jy++) {
    float wy = fmaxf(1.0f - fabsf(sfy - (float)jy) / KS, 0.0f);
    wsy += wy;
    if (wy > 0.0f) {
      const float* row = procL + jy * D;
      float rs = 0.0f;
      for (int jx = x0; jx <= x1; jx++) {
        float wx = fmaxf(1.0f - fabsf(sfx - (float)jx) / KS, 0.0f);
        if (wx > 0.0f) {
          float v = row[jx];
          float tv = (pr == 0.0f) ? 0.0f : ((v - mnv) / pr);
          tv = (tv < 0.2f) ? 0.0f : tv;
          rs += wx * tv;
        }
      }
      acc += wy * rs;
    }
  }
  return acc / (wsy * wsx);
}
__global__ void kF(P p) {
  float* ws = p.ws;
  int b = blockIdx.x, l = b / 225;
  int px = (b - l * 225) * TPB + threadIdx.x;
  float res;
  switch (l) {
    case 0: res = bodyF<0>(px, ws); break;
    case 1: res = bodyF<1>(px, ws); break;
    case 2: res = bodyF<2>(px, ws); break;
    case 3: res = bodyF<3>(px, ws); break;
    default: res = bodyF<4>(px, ws); break;
  }
  ws[O_RESZ + l * 57600 + px] = res;
  float mn = res, mx = res, s = res;
  for (int o = 32; o; o >>= 1) {
    mn = fminf(mn, __shfl_down(mn, o));
    mx = fmaxf(mx, __shfl_down(mx, o));
    s += __shfl_down(s, o);
  }
  __shared__ float smn[4], smx[4], ssm[4];
  int t = threadIdx.x, w = t >> 6;
  if ((t & 63) == 0) { smn[w] = mn; smx[w] = mx; ssm[w] = s; }
  __syncthreads();
  if (t == 0) {
    mn = fminf(fminf(smn[0], smn[1]), fminf(smn[2], smn[3]));
    mx = fmaxf(fmaxf(smx[0], smx[1]), fmaxf(smx[2], smx[3]));
    s = ssm[0] + ssm[1] + ssm[2] + ssm[3];
    atomicMin((unsigned*)ws + O_S3MIN + l, __float_as_uint(mn));
    atomicMax((unsigned*)ws + O_S3MAX + l, __float_as_uint(mx));
    atomicAdd(ws + O_S3SUM + l, s);
  }
}

// ---------------- G2: final ponder + normalize(.,0,256), groups + sum ----------------
__global__ void kG2(P p, float* __restrict__ out) {
  float* ws = p.ws;
  int px = blockIdx.x * TPB + threadIdx.x;   // 225*256 == 57600
  float sum = 0.0f;
  #pragma unroll
  for (int l = 0; l < 5; l++) {
    float v = ws[O_RESZ + l * 57600 + px];
    float mn3 = __uint_as_float(((unsigned*)ws)[O_S3MIN + l]);
    float mx3 = __uint_as_float(((unsigned*)ws)[O_S3MAX + l]);
    float mean3 = ws[O_S3SUM + l] / 57600.0f;
    float r3 = mx3 - mn3;
    float ov;
    if (r3 == 0.0f) ov = 0.0f;
    else {
      float w3 = mx3 - mean3; w3 *= w3;
      if (w3 == 0.0f) ov = 0.0f;
      else ov = ((v - mn3) / r3) * w3 / w3 * 256.0f;
    }
    out[57600 + px * 5 + l] = ov;
    sum += ov;
  }
  out[px] = sum;
}

extern "C" void kernel_launch(void* const* d_in, const int* in_sizes, int n_in,
                              void* d_out, int out_size, void* d_ws, size_t ws_size,
                              hipStream_t stream) {
  (void)in_sizes; (void)n_in; (void)out_size; (void)ws_size;
  P p;
  for (int i = 0; i < 5; i++) p.in[i] = (const float*)d_in[i];
  p.ws = (float*)d_ws;
  float* out = (float*)d_out;

  k_init<<<(N_INIT + TPB - 1) / TPB, TPB, 0, stream>>>(p.ws);
  kA  <<<2752, TPB, 0, stream>>>(p);
  kB  <<<2752, TPB, 0, stream>>>(p);
  kS  <<<6,    TPB, 0, stream>>>(p);
  kC  <<<1730, TPB, 0, stream>>>(p);
  kD  <<<21,   TPB, 0, stream>>>(p);
  kF  <<<1125, TPB, 0, stream>>>(p);
  kG2 <<<225,  TPB, 0, stream>>>(p, out);
}